// Round 7
// baseline (397.851 us; speedup 1.0000x reference)
//
#include <hip/hip_runtime.h>
#include <cmath>

#define GG 20000
#define NN 2048
#define PP 200
#define SS 128
#define EE 128
#define TN 256
#define NSPLIT 200

typedef __bf16 bf16x8 __attribute__((ext_vector_type(8)));
typedef float f32x16 __attribute__((ext_vector_type(16)));
typedef unsigned short u16x8 __attribute__((ext_vector_type(8)));

// static device scratch
__device__ __align__(16) unsigned g_xTi[(size_t)GG * NN];              // 164 MB (h | l<<16)
__device__ __align__(16) unsigned short g_Wsw[(size_t)PP * 32768];     // 13 MB pre-swizzled
__device__ float g_ctx[(size_t)NN * NSPLIT * EE];                      // 210 MB
__device__ float g_m[NN * NSPLIT];

__device__ __forceinline__ unsigned short f2bf(float f) {
  unsigned u = __builtin_bit_cast(unsigned, f);
  return (unsigned short)((u + 0x7FFFu + ((u >> 16) & 1u)) >> 16);
}
__device__ __forceinline__ float bf2f(unsigned short h) {
  return __builtin_bit_cast(float, (unsigned)h << 16);
}
__device__ __forceinline__ unsigned packhl(float f) {
  unsigned short h = f2bf(f);
  unsigned short l = f2bf(f - bf2f(h));
  return (unsigned)h | ((unsigned)l << 16);
}

// ---------------------------------------------------------------------------
// Phase 0a: transpose x (2048 x 20000) -> xTi (20000 x 2048) interleaved hi/lo
// ---------------------------------------------------------------------------
__global__ __launch_bounds__(256) void transpose_convert_kernel(
    const float* __restrict__ x)
{
  __shared__ float tile[64][65];
  const int g0 = blockIdx.x * 64;
  const int n0 = blockIdx.y * 64;
  const int t = threadIdx.x;
  {
    const int gq = t & 15, nl4 = t >> 4;
    #pragma unroll
    for (int k = 0; k < 4; ++k) {
      int nl = nl4 + 16 * k;
      int g = g0 + gq * 4;
      if (g + 3 < GG) {
        float4 v = *(const float4*)&x[(size_t)(n0 + nl) * GG + g];
        tile[gq * 4 + 0][nl] = v.x;
        tile[gq * 4 + 1][nl] = v.y;
        tile[gq * 4 + 2][nl] = v.z;
        tile[gq * 4 + 3][nl] = v.w;
      }
    }
  }
  __syncthreads();
  {
    const int nq = t & 15, gl4 = t >> 4;
    #pragma unroll
    for (int k = 0; k < 4; ++k) {
      int gl = gl4 + 16 * k;
      int g = g0 + gl;
      if (g < GG) {
        uint4 v;
        v.x = packhl(tile[gl][nq * 4 + 0]);
        v.y = packhl(tile[gl][nq * 4 + 1]);
        v.z = packhl(tile[gl][nq * 4 + 2]);
        v.w = packhl(tile[gl][nq * 4 + 3]);
        *(uint4*)&g_xTi[(size_t)g * NN + n0 + nq * 4] = v;
      }
    }
  }
}

// ---------------------------------------------------------------------------
// Phase 0b: W_proj -> pre-swizzled bf16 hi/lo image (LDS-linear order).
// Per (p,ch): h-block 8192 shorts then l-block; offset = e*64 + slp*8 + si
// holding W[p][e][ch*64 + (slp^(e&7))*8 + si].
// ---------------------------------------------------------------------------
__global__ __launch_bounds__(256) void wconvert_kernel(const float* __restrict__ Wp)
{
  unsigned v = blockIdx.x * 256 + threadIdx.x;   // [0, 200*16384)
  const int si = v & 7;
  const int slp = (v >> 3) & 7;
  const int e = (v >> 6) & 127;
  const int ch = (v >> 13) & 1;
  const int p = v >> 14;
  const int slot = slp ^ (e & 7);
  const int s = ch * 64 + slot * 8 + si;
  float f = Wp[((size_t)p * EE + e) * SS + s];
  unsigned short h = f2bf(f);
  unsigned short l = f2bf(f - bf2f(h));
  size_t base = (size_t)(p * 2 + ch) * 16384 + e * 64 + slp * 8 + si;
  g_Wsw[base] = h;
  g_Wsw[base + 8192] = l;
}

// ---------------------------------------------------------------------------
// Phase A: one pathway per block.  grid (8, 200), block 512 (8 waves, TN=256).
// 8 waves share one 64 KB W buffer -> 16 waves/CU at 2 blocks/CU.
// Single burst (8 gload_lds for W + 64 x dwords per thread), one drain,
// 96 MFMA, direct scattered float4 C-stores (no LDS transpose).
// ---------------------------------------------------------------------------
__global__ __launch_bounds__(512, 4) void proj_mfma_kernel(
    const int* __restrict__ tidx, const int* __restrict__ pidx,
    const float* __restrict__ bp, const float* __restrict__ tt)
{
  __shared__ __align__(16) unsigned short wbuf[32768];   // 64 KB
  __shared__ int sidx[SS];
  __shared__ float sbp[EE];

  const int t = threadIdx.x;
  const int w = t >> 6;            // 0..7
  const int ln = t & 63;
  const int nl = ln & 31;
  const int kh = ln >> 5;
  const int n0 = blockIdx.x * TN;
  const int p = blockIdx.y;
  const int ncol = n0 + w * 32 + nl;
  const int tid_n = tidx[ncol];

  if (t < 128) sidx[t] = pidx[p * SS + t];
  else if (t < 256) sbp[t - 128] = bp[p * EE + (t - 128)];
  __syncthreads();

  // --- stage whole W pathway (64 KB): wave w stages shorts [w*4096, +4096)
  {
    const unsigned short* src = g_Wsw + (size_t)p * 32768 + w * 4096 + ln * 8;
    unsigned short* dst = wbuf + w * 4096;   // wave-uniform; HW adds lane*16B
    #pragma unroll
    for (int j = 0; j < 8; ++j) {
      __builtin_amdgcn_global_load_lds(
          (const __attribute__((address_space(1))) unsigned int*)(src + j * 512),
          (__attribute__((address_space(3))) unsigned int*)(dst + j * 512), 16, 0, 0);
    }
  }

  // --- all x loads for this pathway (64 dwords, 128B-coalesced per half-wave)
  unsigned xr[64];
  #pragma unroll
  for (int ks = 0; ks < 8; ++ks)
    #pragma unroll
    for (int j = 0; j < 8; ++j) {
      int s = ks * 16 + kh * 8 + j;
      int g = sidx[s];
      xr[ks * 8 + j] = g_xTi[(size_t)g * NN + ncol];
    }
  __syncthreads();   // single full drain: W in LDS, x in regs

  f32x16 acc[4];
  #pragma unroll
  for (int et = 0; et < 4; ++et)
    #pragma unroll
    for (int r = 0; r < 16; ++r) acc[et][r] = 0.f;

  #pragma unroll
  for (int ks = 0; ks < 8; ++ks) {
    const unsigned short* wAh = wbuf + (ks >> 2) * 16384;
    const unsigned short* wAl = wAh + 8192;
    const int ksl = ks & 3;
    u16x8 bhu, blu;
    #pragma unroll
    for (int j = 0; j < 8; ++j) {
      unsigned v = xr[ks * 8 + j];
      bhu[j] = (unsigned short)(v & 0xffffu);
      blu[j] = (unsigned short)(v >> 16);
    }
    bf16x8 bh = __builtin_bit_cast(bf16x8, bhu);
    bf16x8 bl = __builtin_bit_cast(bf16x8, blu);
    #pragma unroll
    for (int et = 0; et < 4; ++et) {
      const int e = et * 32 + nl;
      const int slp = (ksl * 2 + kh) ^ (e & 7);
      bf16x8 ah = __builtin_bit_cast(bf16x8, *(const uint4*)(wAh + e * 64 + slp * 8));
      bf16x8 al = __builtin_bit_cast(bf16x8, *(const uint4*)(wAl + e * 64 + slp * 8));
      acc[et] = __builtin_amdgcn_mfma_f32_32x32x16_bf16(ah, bh, acc[et], 0, 0, 0);
      acc[et] = __builtin_amdgcn_mfma_f32_32x32x16_bf16(ah, bl, acc[et], 0, 0, 0);
      acc[et] = __builtin_amdgcn_mfma_f32_32x32x16_bf16(al, bh, acc[et], 0, 0, 0);
    }
  }

  // --- bias + relu + score, direct C-stores
  const float4* qp = (const float4*)(tt + (size_t)tid_n * EE);
  float* dst = g_ctx + ((size_t)ncol * NSPLIT + p) * EE;
  float scr = 0.f;
  #pragma unroll
  for (int et = 0; et < 4; ++et)
    #pragma unroll
    for (int rq = 0; rq < 4; ++rq) {
      int e0 = et * 32 + rq * 8 + kh * 4;
      float4 q4 = qp[e0 >> 2];
      float4 b4 = *(const float4*)&sbp[e0];
      float h0 = fmaxf(acc[et][rq * 4 + 0] + b4.x, 0.f);
      float h1 = fmaxf(acc[et][rq * 4 + 1] + b4.y, 0.f);
      float h2 = fmaxf(acc[et][rq * 4 + 2] + b4.z, 0.f);
      float h3 = fmaxf(acc[et][rq * 4 + 3] + b4.w, 0.f);
      scr += h0 * q4.x + h1 * q4.y + h2 * q4.z + h3 * q4.w;
      *(float4*)&dst[e0] = make_float4(h0, h1, h2, h3);
    }
  scr += __shfl_xor(scr, 32);
  if (ln < 32) g_m[(size_t)ncol * NSPLIT + p] = scr * 0.08838834764831845f;
}

// ---------------------------------------------------------------------------
// Phase B: softmax over 200 + MLP + pcn/ang + rec.  grid 2048, block 256.
// ---------------------------------------------------------------------------
__global__ __launch_bounds__(256) void combine_rec_kernel(
    const float* __restrict__ W1, const float* __restrict__ b1,
    const float* __restrict__ W2, const float* __restrict__ b2,
    const float* __restrict__ Wdec, const float* __restrict__ bdec,
    float* __restrict__ out)
{
  const int n = blockIdx.x;
  const int t = threadIdx.x;
  __shared__ float ws[NSPLIT];
  __shared__ float ctx2[2][EE];
  __shared__ float r1[4], r2[4];
  __shared__ float hsh[32];
  __shared__ float qsh[2];
  __shared__ float red[4];

  float mv = (t < NSPLIT) ? g_m[(size_t)n * NSPLIT + t] : -1e30f;
  float M = mv;
  #pragma unroll
  for (int off = 32; off >= 1; off >>= 1) M = fmaxf(M, __shfl_xor(M, off));
  if ((t & 63) == 0) r1[t >> 6] = M;
  __syncthreads();
  M = fmaxf(fmaxf(r1[0], r1[1]), fmaxf(r1[2], r1[3]));
  float wv = (t < NSPLIT) ? expf(mv - M) : 0.f;
  if (t < NSPLIT) ws[t] = wv;
  float L = wv;
  #pragma unroll
  for (int off = 32; off >= 1; off >>= 1) L += __shfl_xor(L, off);
  if ((t & 63) == 0) r2[t >> 6] = L;
  __syncthreads();               // ws visible + r2 ready
  L = r2[0] + r2[1] + r2[2] + r2[3];

  {
    const int e = t & 127, hf = t >> 7;
    const float* base = g_ctx + ((size_t)n * NSPLIT + hf * 100) * EE + e;
    float c = 0.f;
    #pragma unroll 4
    for (int s = 0; s < 100; ++s) c += ws[hf * 100 + s] * base[(size_t)s * EE];
    ctx2[hf][e] = c;
  }
  __syncthreads();
  const float invL = 1.f / L;
  if (t < 32) {
    float h = 0.f;
    for (int e = 0; e < EE; ++e) h += (ctx2[0][e] + ctx2[1][e]) * W1[e * 32 + t];
    hsh[t] = fmaxf(h * invL + b1[t], 0.f);
  }
  __syncthreads();
  if (t == 0) {
    float p0 = b2[0], p1 = b2[1];
    #pragma unroll
    for (int k = 0; k < 32; ++k) { p0 += hsh[k] * W2[k * 2]; p1 += hsh[k] * W2[k * 2 + 1]; }
    float inv = 1.f / fmaxf(sqrtf(p0 * p0 + p1 * p1), 1e-12f);
    float q0 = p0 * inv, q1 = p1 * inv;
    const float PI2 = 6.2831853071795864769f;
    float ang = atan2f(q1, q0) + PI2;
    if (ang >= PI2) ang -= PI2;
    out[n * 2 + 0] = q0;
    out[n * 2 + 1] = q1;
    out[2 * NN + n] = ang;
    qsh[0] = q0; qsh[1] = q1;
  }
  __syncthreads();
  const float q0 = qsh[0], q1 = qsh[1];

  float ss = 0.f;
  for (int i = t; i < GG / 4; i += 256) {
    float4 w0 = *(const float4*)&Wdec[i * 4];
    float4 w1 = *(const float4*)&Wdec[GG + i * 4];
    float4 bd = *(const float4*)&bdec[i * 4];
    float v0 = q0 * w0.x + q1 * w1.x + bd.x;
    float v1 = q0 * w0.y + q1 * w1.y + bd.y;
    float v2 = q0 * w0.z + q1 * w1.z + bd.z;
    float v3 = q0 * w0.w + q1 * w1.w + bd.w;
    ss += v0 * v0 + v1 * v1 + v2 * v2 + v3 * v3;
  }
  #pragma unroll
  for (int off = 32; off >= 1; off >>= 1) ss += __shfl_xor(ss, off);
  if ((t & 63) == 0) red[t >> 6] = ss;
  __syncthreads();
  const float inv = 1.f / fmaxf(sqrtf(red[0] + red[1] + red[2] + red[3]), 1e-12f);

  float* orec = out + 3 * NN + (size_t)n * GG;
  for (int i = t; i < GG / 4; i += 256) {
    float4 w0 = *(const float4*)&Wdec[i * 4];
    float4 w1 = *(const float4*)&Wdec[GG + i * 4];
    float4 bd = *(const float4*)&bdec[i * 4];
    float4 o;
    o.x = (q0 * w0.x + q1 * w1.x + bd.x) * inv;
    o.y = (q0 * w0.y + q1 * w1.y + bd.y) * inv;
    o.z = (q0 * w0.z + q1 * w1.z + bd.z) * inv;
    o.w = (q0 * w0.w + q1 * w1.w + bd.w) * inv;
    *(float4*)&orec[i * 4] = o;
  }
}

// ---------------------------------------------------------------------------
extern "C" void kernel_launch(void* const* d_in, const int* in_sizes, int n_in,
                              void* d_out, int out_size, void* d_ws, size_t ws_size,
                              hipStream_t stream) {
  (void)in_sizes; (void)n_in; (void)out_size; (void)d_ws; (void)ws_size;
  const float* x    = (const float*)d_in[0];
  const int*   tidx = (const int*)  d_in[1];
  const int*   pidx = (const int*)  d_in[2];
  const float* Wp   = (const float*)d_in[3];
  const float* bp   = (const float*)d_in[4];
  const float* tt   = (const float*)d_in[5];
  const float* W1   = (const float*)d_in[6];
  const float* b1   = (const float*)d_in[7];
  const float* W2   = (const float*)d_in[8];
  const float* b2   = (const float*)d_in[9];
  const float* Wdec = (const float*)d_in[10];
  const float* bdec = (const float*)d_in[11];
  float* out = (float*)d_out;

  dim3 gridT((GG + 63) / 64, NN / 64, 1);   // 313 x 32
  transpose_convert_kernel<<<gridT, 256, 0, stream>>>(x);
  wconvert_kernel<<<(PP * 16384) / 256, 256, 0, stream>>>(Wp);

  dim3 gridA(NN / TN, NSPLIT, 1);           // 8 x 200
  proj_mfma_kernel<<<gridA, 512, 0, stream>>>(tidx, pidx, bp, tt);

  combine_rec_kernel<<<NN, 256, 0, stream>>>(W1, b1, W2, b2, Wdec, bdec, out);
}

// Round 8
// 320.609 us; speedup vs baseline: 1.2409x; 1.2409x over previous
//
#include <hip/hip_runtime.h>
#include <cmath>

#define GG 20000
#define NN 2048
#define PP 200
#define SS 128
#define EE 128
#define TN 128
#define NPAIR 100

typedef __bf16 bf16x8 __attribute__((ext_vector_type(8)));
typedef float f32x16 __attribute__((ext_vector_type(16)));
typedef unsigned short u16x8 __attribute__((ext_vector_type(8)));

// static device scratch
__device__ __align__(16) unsigned g_xTi[(size_t)GG * NN];            // 164 MB (h | l<<16)
__device__ __align__(16) unsigned short g_Wsw[(size_t)PP * 32768];   // 13 MB pre-swizzled
__device__ float g_ctxp[(size_t)NN * NPAIR * EE];                    // 105 MB pair partials
__device__ float g_mT[NPAIR * NN];
__device__ float g_lT[NPAIR * NN];

__device__ __forceinline__ unsigned short f2bf(float f) {
  unsigned u = __builtin_bit_cast(unsigned, f);
  return (unsigned short)((u + 0x7FFFu + ((u >> 16) & 1u)) >> 16);
}
__device__ __forceinline__ float bf2f(unsigned short h) {
  return __builtin_bit_cast(float, (unsigned)h << 16);
}
__device__ __forceinline__ unsigned packhl(float f) {
  unsigned short h = f2bf(f);
  unsigned short l = f2bf(f - bf2f(h));
  return (unsigned)h | ((unsigned)l << 16);
}

// ---------------------------------------------------------------------------
// Phase 0a: transpose x (2048 x 20000) -> xTi (20000 x 2048) interleaved hi/lo
// ---------------------------------------------------------------------------
__global__ __launch_bounds__(256) void transpose_convert_kernel(
    const float* __restrict__ x)
{
  __shared__ float tile[64][65];
  const int g0 = blockIdx.x * 64;
  const int n0 = blockIdx.y * 64;
  const int t = threadIdx.x;
  {
    const int gq = t & 15, nl4 = t >> 4;
    #pragma unroll
    for (int k = 0; k < 4; ++k) {
      int nl = nl4 + 16 * k;
      int g = g0 + gq * 4;
      if (g + 3 < GG) {
        float4 v = *(const float4*)&x[(size_t)(n0 + nl) * GG + g];
        tile[gq * 4 + 0][nl] = v.x;
        tile[gq * 4 + 1][nl] = v.y;
        tile[gq * 4 + 2][nl] = v.z;
        tile[gq * 4 + 3][nl] = v.w;
      }
    }
  }
  __syncthreads();
  {
    const int nq = t & 15, gl4 = t >> 4;
    #pragma unroll
    for (int k = 0; k < 4; ++k) {
      int gl = gl4 + 16 * k;
      int g = g0 + gl;
      if (g < GG) {
        uint4 v;
        v.x = packhl(tile[gl][nq * 4 + 0]);
        v.y = packhl(tile[gl][nq * 4 + 1]);
        v.z = packhl(tile[gl][nq * 4 + 2]);
        v.w = packhl(tile[gl][nq * 4 + 3]);
        *(uint4*)&g_xTi[(size_t)g * NN + n0 + nq * 4] = v;
      }
    }
  }
}

// ---------------------------------------------------------------------------
// Phase 0b: W_proj -> pre-swizzled bf16 hi/lo image (LDS-linear order).
// Per (p,ch): h-block 8192 shorts then l-block; offset = e*64 + slp*8 + si
// holding W[p][e][ch*64 + (slp^(e&7))*8 + si].
// ---------------------------------------------------------------------------
__global__ __launch_bounds__(256) void wconvert_kernel(const float* __restrict__ Wp)
{
  unsigned v = blockIdx.x * 256 + threadIdx.x;   // [0, 200*16384)
  const int si = v & 7;
  const int slp = (v >> 3) & 7;
  const int e = (v >> 6) & 127;
  const int ch = (v >> 13) & 1;
  const int p = v >> 14;
  const int slot = slp ^ (e & 7);
  const int s = ch * 64 + slot * 8 + si;
  float f = Wp[((size_t)p * EE + e) * SS + s];
  unsigned short h = f2bf(f);
  unsigned short l = f2bf(f - bf2f(h));
  size_t base = (size_t)(p * 2 + ch) * 16384 + e * 64 + slp * 8 + si;
  g_Wsw[base] = h;
  g_Wsw[base + 8192] = l;
}

// ---------------------------------------------------------------------------
// proj helpers
// ---------------------------------------------------------------------------
__device__ __forceinline__ void load16(unsigned* xr, const int* sidx_lds,
                                       int sbase, int kh, int ncol) {
  #pragma unroll
  for (int ks2 = 0; ks2 < 2; ++ks2)
    #pragma unroll
    for (int j = 0; j < 8; ++j) {
      int s = (sbase + ks2) * 16 + kh * 8 + j;
      xr[ks2 * 8 + j] = g_xTi[(size_t)sidx_lds[s] * NN + ncol];
    }
}

__device__ __forceinline__ void compute2ks(const unsigned short* wb,
                                           const unsigned* xr, f32x16 (&acc)[4],
                                           int ksbase, int nl, int kh) {
  #pragma unroll
  for (int ks2 = 0; ks2 < 2; ++ks2) {
    const int ks = ksbase + ks2;
    const unsigned short* wAh = wb + (ks >> 2) * 16384;
    const unsigned short* wAl = wAh + 8192;
    u16x8 bhu, blu;
    #pragma unroll
    for (int j = 0; j < 8; ++j) {
      unsigned v = xr[ks2 * 8 + j];
      bhu[j] = (unsigned short)(v & 0xffffu);
      blu[j] = (unsigned short)(v >> 16);
    }
    bf16x8 bh = __builtin_bit_cast(bf16x8, bhu);
    bf16x8 bl = __builtin_bit_cast(bf16x8, blu);
    #pragma unroll
    for (int et = 0; et < 4; ++et) {
      const int e = et * 32 + nl;
      const int slp = ((ks & 3) * 2 + kh) ^ (e & 7);
      bf16x8 ah = __builtin_bit_cast(bf16x8, *(const uint4*)(wAh + e * 64 + slp * 8));
      bf16x8 al = __builtin_bit_cast(bf16x8, *(const uint4*)(wAl + e * 64 + slp * 8));
      acc[et] = __builtin_amdgcn_mfma_f32_32x32x16_bf16(ah, bh, acc[et], 0, 0, 0);
      acc[et] = __builtin_amdgcn_mfma_f32_32x32x16_bf16(ah, bl, acc[et], 0, 0, 0);
      acc[et] = __builtin_amdgcn_mfma_f32_32x32x16_bf16(al, bh, acc[et], 0, 0, 0);
    }
  }
}

// one full pathway: stage W+x, 96 MFMA, bias+relu+score.  H left in h[].
__device__ __forceinline__ void pathway_body(
    int p, unsigned short* wbuf, int* sidx, float* sbp,
    const int* __restrict__ pidx, const float* __restrict__ bp,
    const float* __restrict__ tt, int tid_n,
    int t, int w, int ln, int nl, int kh, int ncol,
    f32x16 (&h)[4], float& s_out)
{
  __syncthreads();                 // wbuf+sidx consumed by previous pathway
  if (t < 128) sidx[t] = pidx[p * SS + t];
  else         sbp[t - 128] = bp[p * EE + (t - 128)];
  // stage whole W pathway (64 KB): wave w stages shorts [w*8192, +8192)
  {
    const unsigned short* src = g_Wsw + (size_t)p * 32768 + w * 8192 + ln * 8;
    unsigned short* dst = wbuf + w * 8192;   // wave-uniform; HW adds lane*16B
    #pragma unroll
    for (int j = 0; j < 16; ++j) {
      __builtin_amdgcn_global_load_lds(
          (const __attribute__((address_space(1))) unsigned int*)(src + j * 512),
          (__attribute__((address_space(3))) unsigned int*)(dst + j * 512), 16, 0, 0);
    }
  }
  __syncthreads();                 // sidx/sbp visible + W staged (vmcnt drain)

  #pragma unroll
  for (int et = 0; et < 4; ++et)
    #pragma unroll
    for (int r = 0; r < 16; ++r) h[et][r] = 0.f;

  unsigned xa[16], xb[16];
  load16(xa, sidx, 0, kh, ncol);
  load16(xb, sidx, 2, kh, ncol);
  compute2ks(wbuf, xa, h, 0, nl, kh);
  load16(xa, sidx, 4, kh, ncol);
  compute2ks(wbuf, xb, h, 2, nl, kh);
  load16(xb, sidx, 6, kh, ncol);
  compute2ks(wbuf, xa, h, 4, nl, kh);
  compute2ks(wbuf, xb, h, 6, nl, kh);

  // bias + relu + score (per-lane column n)
  const float4* qp = (const float4*)(tt + (size_t)tid_n * EE);
  float scr = 0.f;
  #pragma unroll
  for (int et = 0; et < 4; ++et)
    #pragma unroll
    for (int rq = 0; rq < 4; ++rq) {
      int e0 = et * 32 + rq * 8 + kh * 4;
      float4 q4 = qp[e0 >> 2];
      float4 b4 = *(const float4*)&sbp[e0];
      float h0 = fmaxf(h[et][rq * 4 + 0] + b4.x, 0.f);
      float h1 = fmaxf(h[et][rq * 4 + 1] + b4.y, 0.f);
      float h2 = fmaxf(h[et][rq * 4 + 2] + b4.z, 0.f);
      float h3 = fmaxf(h[et][rq * 4 + 3] + b4.w, 0.f);
      h[et][rq * 4 + 0] = h0; h[et][rq * 4 + 1] = h1;
      h[et][rq * 4 + 2] = h2; h[et][rq * 4 + 3] = h3;
      scr += h0 * q4.x + h1 * q4.y + h2 * q4.z + h3 * q4.w;
    }
  scr += __shfl_xor(scr, 32);
  s_out = scr * 0.08838834764831845f;   // 1/sqrt(128)
}

// ---------------------------------------------------------------------------
// Phase A: TWO pathways per block, pair-combined in-register.
// grid (16, 100), block 256 (4 waves).  Writes one fp32 partial ctx per pair
// (coalesced via LDS transpose) + (m, l) per (pair, n).
// ---------------------------------------------------------------------------
__global__ __launch_bounds__(256, 2) void proj_mfma_kernel(
    const int* __restrict__ tidx, const int* __restrict__ pidx,
    const float* __restrict__ bp, const float* __restrict__ tt)
{
  __shared__ __align__(16) unsigned short wbuf[32768];   // 64 KB
  __shared__ int sidx[SS];
  __shared__ float sbp[EE];

  const int t = threadIdx.x;
  const int w = t >> 6;
  const int ln = t & 63;
  const int nl = ln & 31;
  const int kh = ln >> 5;
  const int n0 = blockIdx.x * TN;
  const int pair = blockIdx.y;
  const int ncol = n0 + w * 32 + nl;
  const int tid_n = tidx[ncol];

  f32x16 h0[4], h1[4];
  float s0, s1;
  pathway_body(pair * 2 + 0, wbuf, sidx, sbp, pidx, bp, tt, tid_n,
               t, w, ln, nl, kh, ncol, h0, s0);
  pathway_body(pair * 2 + 1, wbuf, sidx, sbp, pidx, bp, tt, tid_n,
               t, w, ln, nl, kh, ncol, h1, s1);

  // pair-local softmax combine (exact): ctx_p = w0*H0 + w1*H1
  const float m = fmaxf(s0, s1);
  const float w0 = expf(s0 - m);
  const float w1 = expf(s1 - m);
  const float lsum = w0 + w1;
  #pragma unroll
  for (int et = 0; et < 4; ++et)
    #pragma unroll
    for (int r = 0; r < 16; ++r)
      h0[et][r] = w0 * h0[et][r] + w1 * h1[et][r];

  // epilogue: LDS transpose -> coalesced 512B row stores
  __syncthreads();                 // all waves done reading wbuf
  float* tb = ((float*)wbuf) + w * (32 * 128);
  #pragma unroll
  for (int et = 0; et < 4; ++et)
    #pragma unroll
    for (int rq = 0; rq < 4; ++rq) {
      int slot = et * 8 + rq * 2 + kh;          // e-quad index 0..31
      float4 v = make_float4(h0[et][rq * 4 + 0], h0[et][rq * 4 + 1],
                             h0[et][rq * 4 + 2], h0[et][rq * 4 + 3]);
      *(float4*)&tb[nl * 128 + ((slot ^ nl) << 2)] = v;
    }
  __syncthreads();
  {
    const int rrow = ln >> 1, eh = (ln & 1) * 16;
    const int nn = n0 + w * 32 + rrow;
    float* dst = g_ctxp + ((size_t)nn * NPAIR + pair) * EE + eh * 4;
    const float* srcrow = tb + rrow * 128;
    #pragma unroll
    for (int k = 0; k < 16; ++k) {
      int slot = eh + k;
      *(float4*)&dst[k * 4] = *(const float4*)&srcrow[(slot ^ rrow) << 2];
    }
  }
  if (ln < 32) {
    g_mT[pair * NN + ncol] = m;
    g_lT[pair * NN + ncol] = lsum;
  }
}

// ---------------------------------------------------------------------------
// Phase B: merge 100 pair-partials + MLP + pcn/ang + rec.  grid 2048, blk 256.
// ---------------------------------------------------------------------------
__global__ __launch_bounds__(256) void combine_rec_kernel(
    const float* __restrict__ W1, const float* __restrict__ b1,
    const float* __restrict__ W2, const float* __restrict__ b2,
    const float* __restrict__ Wdec, const float* __restrict__ bdec,
    float* __restrict__ out)
{
  const int n = blockIdx.x;
  const int t = threadIdx.x;
  __shared__ float ws[NPAIR];
  __shared__ float ctx2[2][EE];
  __shared__ float r1[4], r2[4];
  __shared__ float hsh[32];
  __shared__ float qsh[2];
  __shared__ float red[4];

  float mv = (t < NPAIR) ? g_mT[t * NN + n] : -1e30f;
  float lv = (t < NPAIR) ? g_lT[t * NN + n] : 0.f;
  float M = mv;
  #pragma unroll
  for (int off = 32; off >= 1; off >>= 1) M = fmaxf(M, __shfl_xor(M, off));
  if ((t & 63) == 0) r1[t >> 6] = M;
  __syncthreads();
  M = fmaxf(fmaxf(r1[0], r1[1]), fmaxf(r1[2], r1[3]));
  float wv = (t < NPAIR) ? expf(mv - M) : 0.f;
  if (t < NPAIR) ws[t] = wv;
  float Lp = wv * lv;
  #pragma unroll
  for (int off = 32; off >= 1; off >>= 1) Lp += __shfl_xor(Lp, off);
  if ((t & 63) == 0) r2[t >> 6] = Lp;
  __syncthreads();               // ws visible + r2 ready
  const float L = r2[0] + r2[1] + r2[2] + r2[3];

  {
    const int e = t & 127, hf = t >> 7;
    const float* base = g_ctxp + ((size_t)n * NPAIR + hf * 50) * EE + e;
    float c = 0.f;
    #pragma unroll 5
    for (int s = 0; s < 50; ++s) c += ws[hf * 50 + s] * base[(size_t)s * EE];
    ctx2[hf][e] = c;
  }
  __syncthreads();
  const float invL = 1.f / L;
  if (t < 32) {
    float h = 0.f;
    for (int e = 0; e < EE; ++e) h += (ctx2[0][e] + ctx2[1][e]) * W1[e * 32 + t];
    hsh[t] = fmaxf(h * invL + b1[t], 0.f);
  }
  __syncthreads();
  if (t == 0) {
    float p0 = b2[0], p1 = b2[1];
    #pragma unroll
    for (int k = 0; k < 32; ++k) { p0 += hsh[k] * W2[k * 2]; p1 += hsh[k] * W2[k * 2 + 1]; }
    float inv = 1.f / fmaxf(sqrtf(p0 * p0 + p1 * p1), 1e-12f);
    float q0 = p0 * inv, q1 = p1 * inv;
    const float PI2 = 6.2831853071795864769f;
    float ang = atan2f(q1, q0) + PI2;
    if (ang >= PI2) ang -= PI2;
    out[n * 2 + 0] = q0;
    out[n * 2 + 1] = q1;
    out[2 * NN + n] = ang;
    qsh[0] = q0; qsh[1] = q1;
  }
  __syncthreads();
  const float q0 = qsh[0], q1 = qsh[1];

  float ss = 0.f;
  for (int i = t; i < GG / 4; i += 256) {
    float4 w0 = *(const float4*)&Wdec[i * 4];
    float4 w1 = *(const float4*)&Wdec[GG + i * 4];
    float4 bd = *(const float4*)&bdec[i * 4];
    float v0 = q0 * w0.x + q1 * w1.x + bd.x;
    float v1 = q0 * w0.y + q1 * w1.y + bd.y;
    float v2 = q0 * w0.z + q1 * w1.z + bd.z;
    float v3 = q0 * w0.w + q1 * w1.w + bd.w;
    ss += v0 * v0 + v1 * v1 + v2 * v2 + v3 * v3;
  }
  #pragma unroll
  for (int off = 32; off >= 1; off >>= 1) ss += __shfl_xor(ss, off);
  if ((t & 63) == 0) red[t >> 6] = ss;
  __syncthreads();
  const float inv = 1.f / fmaxf(sqrtf(red[0] + red[1] + red[2] + red[3]), 1e-12f);

  float* orec = out + 3 * NN + (size_t)n * GG;
  for (int i = t; i < GG / 4; i += 256) {
    float4 w0 = *(const float4*)&Wdec[i * 4];
    float4 w1 = *(const float4*)&Wdec[GG + i * 4];
    float4 bd = *(const float4*)&bdec[i * 4];
    float4 o;
    o.x = (q0 * w0.x + q1 * w1.x + bd.x) * inv;
    o.y = (q0 * w0.y + q1 * w1.y + bd.y) * inv;
    o.z = (q0 * w0.z + q1 * w1.z + bd.z) * inv;
    o.w = (q0 * w0.w + q1 * w1.w + bd.w) * inv;
    *(float4*)&orec[i * 4] = o;
  }
}

// ---------------------------------------------------------------------------
extern "C" void kernel_launch(void* const* d_in, const int* in_sizes, int n_in,
                              void* d_out, int out_size, void* d_ws, size_t ws_size,
                              hipStream_t stream) {
  (void)in_sizes; (void)n_in; (void)out_size; (void)d_ws; (void)ws_size;
  const float* x    = (const float*)d_in[0];
  const int*   tidx = (const int*)  d_in[1];
  const int*   pidx = (const int*)  d_in[2];
  const float* Wp   = (const float*)d_in[3];
  const float* bp   = (const float*)d_in[4];
  const float* tt   = (const float*)d_in[5];
  const float* W1   = (const float*)d_in[6];
  const float* b1   = (const float*)d_in[7];
  const float* W2   = (const float*)d_in[8];
  const float* b2   = (const float*)d_in[9];
  const float* Wdec = (const float*)d_in[10];
  const float* bdec = (const float*)d_in[11];
  float* out = (float*)d_out;

  dim3 gridT((GG + 63) / 64, NN / 64, 1);   // 313 x 32
  transpose_convert_kernel<<<gridT, 256, 0, stream>>>(x);
  wconvert_kernel<<<(PP * 16384) / 256, 256, 0, stream>>>(Wp);

  dim3 gridA(NN / TN, NPAIR, 1);            // 16 x 100
  proj_mfma_kernel<<<gridA, 256, 0, stream>>>(tidx, pidx, bp, tt);

  combine_rec_kernel<<<NN, 256, 0, stream>>>(W1, b1, W2, b2, Wdec, bdec, out);
}

// Round 9
// 286.200 us; speedup vs baseline: 1.3901x; 1.1202x over previous
//
#include <hip/hip_runtime.h>
#include <cmath>

#define GG 20000
#define NN 2048
#define PP 200
#define SS 128
#define EE 128
#define TN 128
#define TPP 8
#define NOCT 25

typedef __bf16 bf16x8 __attribute__((ext_vector_type(8)));
typedef float f32x16 __attribute__((ext_vector_type(16)));
typedef unsigned short u16x8 __attribute__((ext_vector_type(8)));

// static device scratch
__device__ __align__(16) unsigned g_xTi[(size_t)GG * NN];            // 164 MB (h | l<<16)
__device__ __align__(16) unsigned short g_Wsw[(size_t)PP * 32768];   // 13 MB pre-swizzled
__device__ float g_ctxp[(size_t)NN * NOCT * EE];                     // 26 MB octet partials
__device__ float g_mT[NOCT * NN];
__device__ float g_lT[NOCT * NN];

__device__ __forceinline__ unsigned short f2bf(float f) {
  unsigned u = __builtin_bit_cast(unsigned, f);
  return (unsigned short)((u + 0x7FFFu + ((u >> 16) & 1u)) >> 16);
}
__device__ __forceinline__ float bf2f(unsigned short h) {
  return __builtin_bit_cast(float, (unsigned)h << 16);
}
__device__ __forceinline__ unsigned packhl(float f) {
  unsigned short h = f2bf(f);
  unsigned short l = f2bf(f - bf2f(h));
  return (unsigned)h | ((unsigned)l << 16);
}

// ---------------------------------------------------------------------------
// Phase 0a: transpose x (2048 x 20000) -> xTi (20000 x 2048) interleaved hi/lo
// ---------------------------------------------------------------------------
__global__ __launch_bounds__(256) void transpose_convert_kernel(
    const float* __restrict__ x)
{
  __shared__ float tile[64][65];
  const int g0 = blockIdx.x * 64;
  const int n0 = blockIdx.y * 64;
  const int t = threadIdx.x;
  {
    const int gq = t & 15, nl4 = t >> 4;
    #pragma unroll
    for (int k = 0; k < 4; ++k) {
      int nl = nl4 + 16 * k;
      int g = g0 + gq * 4;
      if (g + 3 < GG) {
        float4 v = *(const float4*)&x[(size_t)(n0 + nl) * GG + g];
        tile[gq * 4 + 0][nl] = v.x;
        tile[gq * 4 + 1][nl] = v.y;
        tile[gq * 4 + 2][nl] = v.z;
        tile[gq * 4 + 3][nl] = v.w;
      }
    }
  }
  __syncthreads();
  {
    const int nq = t & 15, gl4 = t >> 4;
    #pragma unroll
    for (int k = 0; k < 4; ++k) {
      int gl = gl4 + 16 * k;
      int g = g0 + gl;
      if (g < GG) {
        uint4 v;
        v.x = packhl(tile[gl][nq * 4 + 0]);
        v.y = packhl(tile[gl][nq * 4 + 1]);
        v.z = packhl(tile[gl][nq * 4 + 2]);
        v.w = packhl(tile[gl][nq * 4 + 3]);
        *(uint4*)&g_xTi[(size_t)g * NN + n0 + nq * 4] = v;
      }
    }
  }
}

// ---------------------------------------------------------------------------
// Phase 0b: W_proj -> pre-swizzled bf16 hi/lo image (LDS-linear order).
// ---------------------------------------------------------------------------
__global__ __launch_bounds__(256) void wconvert_kernel(const float* __restrict__ Wp)
{
  unsigned v = blockIdx.x * 256 + threadIdx.x;   // [0, 200*16384)
  const int si = v & 7;
  const int slp = (v >> 3) & 7;
  const int e = (v >> 6) & 127;
  const int ch = (v >> 13) & 1;
  const int p = v >> 14;
  const int slot = slp ^ (e & 7);
  const int s = ch * 64 + slot * 8 + si;
  float f = Wp[((size_t)p * EE + e) * SS + s];
  unsigned short h = f2bf(f);
  unsigned short l = f2bf(f - bf2f(h));
  size_t base = (size_t)(p * 2 + ch) * 16384 + e * 64 + slp * 8 + si;
  g_Wsw[base] = h;
  g_Wsw[base + 8192] = l;
}

// ---------------------------------------------------------------------------
// proj helpers
// ---------------------------------------------------------------------------
__device__ __forceinline__ void load16(unsigned* xr, const int* sidx_lds,
                                       int sbase, int kh, int ncol) {
  #pragma unroll
  for (int ks2 = 0; ks2 < 2; ++ks2)
    #pragma unroll
    for (int j = 0; j < 8; ++j) {
      int s = (sbase + ks2) * 16 + kh * 8 + j;
      xr[ks2 * 8 + j] = g_xTi[(size_t)sidx_lds[s] * NN + ncol];
    }
}

__device__ __forceinline__ void compute2ks(const unsigned short* wb,
                                           const unsigned* xr, f32x16 (&acc)[4],
                                           int ksbase, int nl, int kh) {
  #pragma unroll
  for (int ks2 = 0; ks2 < 2; ++ks2) {
    const int ks = ksbase + ks2;
    const unsigned short* wAh = wb + (ks >> 2) * 16384;
    const unsigned short* wAl = wAh + 8192;
    u16x8 bhu, blu;
    #pragma unroll
    for (int j = 0; j < 8; ++j) {
      unsigned v = xr[ks2 * 8 + j];
      bhu[j] = (unsigned short)(v & 0xffffu);
      blu[j] = (unsigned short)(v >> 16);
    }
    bf16x8 bh = __builtin_bit_cast(bf16x8, bhu);
    bf16x8 bl = __builtin_bit_cast(bf16x8, blu);
    #pragma unroll
    for (int et = 0; et < 4; ++et) {
      const int e = et * 32 + nl;
      const int slp = ((ks & 3) * 2 + kh) ^ (e & 7);
      bf16x8 ah = __builtin_bit_cast(bf16x8, *(const uint4*)(wAh + e * 64 + slp * 8));
      bf16x8 al = __builtin_bit_cast(bf16x8, *(const uint4*)(wAl + e * 64 + slp * 8));
      acc[et] = __builtin_amdgcn_mfma_f32_32x32x16_bf16(ah, bh, acc[et], 0, 0, 0);
      acc[et] = __builtin_amdgcn_mfma_f32_32x32x16_bf16(ah, bl, acc[et], 0, 0, 0);
      acc[et] = __builtin_amdgcn_mfma_f32_32x32x16_bf16(al, bh, acc[et], 0, 0, 0);
    }
  }
}

// one full pathway: stage W+x, 96 MFMA, bias+relu+score.  H left in h[].
__device__ __forceinline__ void pathway_body(
    int p, unsigned short* wbuf, int* sidx, float* sbp,
    const int* __restrict__ pidx, const float* __restrict__ bp,
    const float* __restrict__ tt, int tid_n,
    int t, int w, int ln, int nl, int kh, int ncol,
    f32x16 (&h)[4], float& s_out)
{
  __syncthreads();                 // wbuf/sidx/sbp consumed by previous pathway
  if (t < 128) sidx[t] = pidx[p * SS + t];
  else         sbp[t - 128] = bp[p * EE + (t - 128)];
  // stage whole W pathway (64 KB): wave w stages shorts [w*8192, +8192)
  {
    const unsigned short* src = g_Wsw + (size_t)p * 32768 + w * 8192 + ln * 8;
    unsigned short* dst = wbuf + w * 8192;   // wave-uniform; HW adds lane*16B
    #pragma unroll
    for (int j = 0; j < 16; ++j) {
      __builtin_amdgcn_global_load_lds(
          (const __attribute__((address_space(1))) unsigned int*)(src + j * 512),
          (__attribute__((address_space(3))) unsigned int*)(dst + j * 512), 16, 0, 0);
    }
  }
  __syncthreads();                 // sidx/sbp visible + W staged (vmcnt drain)

  #pragma unroll
  for (int et = 0; et < 4; ++et)
    #pragma unroll
    for (int r = 0; r < 16; ++r) h[et][r] = 0.f;

  unsigned xa[16], xb[16];
  load16(xa, sidx, 0, kh, ncol);
  load16(xb, sidx, 2, kh, ncol);
  compute2ks(wbuf, xa, h, 0, nl, kh);
  load16(xa, sidx, 4, kh, ncol);
  compute2ks(wbuf, xb, h, 2, nl, kh);
  load16(xb, sidx, 6, kh, ncol);
  compute2ks(wbuf, xa, h, 4, nl, kh);
  compute2ks(wbuf, xb, h, 6, nl, kh);

  // bias + relu + score (per-lane column n)
  const float4* qp = (const float4*)(tt + (size_t)tid_n * EE);
  float scr = 0.f;
  #pragma unroll
  for (int et = 0; et < 4; ++et)
    #pragma unroll
    for (int rq = 0; rq < 4; ++rq) {
      int e0 = et * 32 + rq * 8 + kh * 4;
      float4 q4 = qp[e0 >> 2];
      float4 b4 = *(const float4*)&sbp[e0];
      float h0 = fmaxf(h[et][rq * 4 + 0] + b4.x, 0.f);
      float h1 = fmaxf(h[et][rq * 4 + 1] + b4.y, 0.f);
      float h2 = fmaxf(h[et][rq * 4 + 2] + b4.z, 0.f);
      float h3 = fmaxf(h[et][rq * 4 + 3] + b4.w, 0.f);
      h[et][rq * 4 + 0] = h0; h[et][rq * 4 + 1] = h1;
      h[et][rq * 4 + 2] = h2; h[et][rq * 4 + 3] = h3;
      scr += h0 * q4.x + h1 * q4.y + h2 * q4.z + h3 * q4.w;
    }
  scr += __shfl_xor(scr, 32);
  s_out = scr * 0.08838834764831845f;   // 1/sqrt(128)
}

// ---------------------------------------------------------------------------
// Phase A: EIGHT pathways per block, online-softmax combined in registers.
// grid (16, 25), block 256 (4 waves), all 400 blocks co-resident.
// Writes one fp32 partial ctx per octet (coalesced via LDS transpose) + (m,l).
// ---------------------------------------------------------------------------
__global__ __launch_bounds__(256, 2) void proj_mfma_kernel(
    const int* __restrict__ tidx, const int* __restrict__ pidx,
    const float* __restrict__ bp, const float* __restrict__ tt)
{
  __shared__ __align__(16) unsigned short wbuf[32768];   // 64 KB
  __shared__ int sidx[SS];
  __shared__ float sbp[EE];

  const int t = threadIdx.x;
  const int w = t >> 6;
  const int ln = t & 63;
  const int nl = ln & 31;
  const int kh = ln >> 5;
  const int n0 = blockIdx.x * TN;
  const int oct = blockIdx.y;
  const int ncol = n0 + w * 32 + nl;
  const int tid_n = tidx[ncol];

  f32x16 ctx[4];
  #pragma unroll
  for (int et = 0; et < 4; ++et)
    #pragma unroll
    for (int r = 0; r < 16; ++r) ctx[et][r] = 0.f;
  float m_r = -1e30f, l_r = 0.f;

  f32x16 h[4];
  float s;
  for (int pp = 0; pp < TPP; ++pp) {
    pathway_body(oct * TPP + pp, wbuf, sidx, sbp, pidx, bp, tt, tid_n,
                 t, w, ln, nl, kh, ncol, h, s);
    // online softmax update (exact fp32)
    const float mn = fmaxf(m_r, s);
    const float f = expf(m_r - mn);
    const float wg = expf(s - mn);
    l_r = l_r * f + wg;
    m_r = mn;
    #pragma unroll
    for (int et = 0; et < 4; ++et)
      #pragma unroll
      for (int r = 0; r < 16; ++r)
        ctx[et][r] = ctx[et][r] * f + wg * h[et][r];
  }

  // epilogue: LDS transpose -> coalesced 512B row stores
  __syncthreads();                 // all waves done reading wbuf
  float* tb = ((float*)wbuf) + w * (32 * 128);
  #pragma unroll
  for (int et = 0; et < 4; ++et)
    #pragma unroll
    for (int rq = 0; rq < 4; ++rq) {
      int slot = et * 8 + rq * 2 + kh;          // e-quad index 0..31
      float4 v = make_float4(ctx[et][rq * 4 + 0], ctx[et][rq * 4 + 1],
                             ctx[et][rq * 4 + 2], ctx[et][rq * 4 + 3]);
      *(float4*)&tb[nl * 128 + ((slot ^ nl) << 2)] = v;
    }
  __syncthreads();
  {
    const int rrow = ln >> 1, eh = (ln & 1) * 16;
    const int nn = n0 + w * 32 + rrow;
    float* dst = g_ctxp + ((size_t)nn * NOCT + oct) * EE + eh * 4;
    const float* srcrow = tb + rrow * 128;
    #pragma unroll
    for (int k = 0; k < 16; ++k) {
      int slot = eh + k;
      *(float4*)&dst[k * 4] = *(const float4*)&srcrow[(slot ^ rrow) << 2];
    }
  }
  if (ln < 32) {
    g_mT[oct * NN + ncol] = m_r;
    g_lT[oct * NN + ncol] = l_r;
  }
}

// ---------------------------------------------------------------------------
// Phase B: merge 25 octet-partials + MLP + pcn/ang + rec.  grid 2048, blk 256.
// ---------------------------------------------------------------------------
__global__ __launch_bounds__(256) void combine_rec_kernel(
    const float* __restrict__ W1, const float* __restrict__ b1,
    const float* __restrict__ W2, const float* __restrict__ b2,
    const float* __restrict__ Wdec, const float* __restrict__ bdec,
    float* __restrict__ out)
{
  const int n = blockIdx.x;
  const int t = threadIdx.x;
  __shared__ float ws[NOCT];
  __shared__ float ctx2[2][EE];
  __shared__ float r1[4], r2[4];
  __shared__ float hsh[32];
  __shared__ float qsh[2];
  __shared__ float red[4];

  float mv = (t < NOCT) ? g_mT[t * NN + n] : -1e30f;
  float lv = (t < NOCT) ? g_lT[t * NN + n] : 0.f;
  float M = mv;
  #pragma unroll
  for (int off = 32; off >= 1; off >>= 1) M = fmaxf(M, __shfl_xor(M, off));
  if ((t & 63) == 0) r1[t >> 6] = M;
  __syncthreads();
  M = fmaxf(fmaxf(r1[0], r1[1]), fmaxf(r1[2], r1[3]));
  float wv = (t < NOCT) ? expf(mv - M) : 0.f;
  if (t < NOCT) ws[t] = wv;
  float Lp = wv * lv;
  #pragma unroll
  for (int off = 32; off >= 1; off >>= 1) Lp += __shfl_xor(Lp, off);
  if ((t & 63) == 0) r2[t >> 6] = Lp;
  __syncthreads();               // ws visible + r2 ready
  const float L = r2[0] + r2[1] + r2[2] + r2[3];

  {
    const int e = t & 127, hf = t >> 7;
    const int sA = hf ? 13 : 0, sB = hf ? NOCT : 13;
    const float* base = g_ctxp + ((size_t)n * NOCT + sA) * EE + e;
    float c = 0.f;
    for (int s = sA; s < sB; ++s) c += ws[s] * base[(size_t)(s - sA) * EE];
    ctx2[hf][e] = c;
  }
  __syncthreads();
  const float invL = 1.f / L;
  if (t < 32) {
    float h = 0.f;
    for (int e = 0; e < EE; ++e) h += (ctx2[0][e] + ctx2[1][e]) * W1[e * 32 + t];
    hsh[t] = fmaxf(h * invL + b1[t], 0.f);
  }
  __syncthreads();
  if (t == 0) {
    float p0 = b2[0], p1 = b2[1];
    #pragma unroll
    for (int k = 0; k < 32; ++k) { p0 += hsh[k] * W2[k * 2]; p1 += hsh[k] * W2[k * 2 + 1]; }
    float inv = 1.f / fmaxf(sqrtf(p0 * p0 + p1 * p1), 1e-12f);
    float q0 = p0 * inv, q1 = p1 * inv;
    const float PI2 = 6.2831853071795864769f;
    float ang = atan2f(q1, q0) + PI2;
    if (ang >= PI2) ang -= PI2;
    out[n * 2 + 0] = q0;
    out[n * 2 + 1] = q1;
    out[2 * NN + n] = ang;
    qsh[0] = q0; qsh[1] = q1;
  }
  __syncthreads();
  const float q0 = qsh[0], q1 = qsh[1];

  float ss = 0.f;
  for (int i = t; i < GG / 4; i += 256) {
    float4 w0 = *(const float4*)&Wdec[i * 4];
    float4 w1 = *(const float4*)&Wdec[GG + i * 4];
    float4 bd = *(const float4*)&bdec[i * 4];
    float v0 = q0 * w0.x + q1 * w1.x + bd.x;
    float v1 = q0 * w0.y + q1 * w1.y + bd.y;
    float v2 = q0 * w0.z + q1 * w1.z + bd.z;
    float v3 = q0 * w0.w + q1 * w1.w + bd.w;
    ss += v0 * v0 + v1 * v1 + v2 * v2 + v3 * v3;
  }
  #pragma unroll
  for (int off = 32; off >= 1; off >>= 1) ss += __shfl_xor(ss, off);
  if ((t & 63) == 0) red[t >> 6] = ss;
  __syncthreads();
  const float inv = 1.f / fmaxf(sqrtf(red[0] + red[1] + red[2] + red[3]), 1e-12f);

  float* orec = out + 3 * NN + (size_t)n * GG;
  for (int i = t; i < GG / 4; i += 256) {
    float4 w0 = *(const float4*)&Wdec[i * 4];
    float4 w1 = *(const float4*)&Wdec[GG + i * 4];
    float4 bd = *(const float4*)&bdec[i * 4];
    float4 o;
    o.x = (q0 * w0.x + q1 * w1.x + bd.x) * inv;
    o.y = (q0 * w0.y + q1 * w1.y + bd.y) * inv;
    o.z = (q0 * w0.z + q1 * w1.z + bd.z) * inv;
    o.w = (q0 * w0.w + q1 * w1.w + bd.w) * inv;
    *(float4*)&orec[i * 4] = o;
  }
}

// ---------------------------------------------------------------------------
extern "C" void kernel_launch(void* const* d_in, const int* in_sizes, int n_in,
                              void* d_out, int out_size, void* d_ws, size_t ws_size,
                              hipStream_t stream) {
  (void)in_sizes; (void)n_in; (void)out_size; (void)d_ws; (void)ws_size;
  const float* x    = (const float*)d_in[0];
  const int*   tidx = (const int*)  d_in[1];
  const int*   pidx = (const int*)  d_in[2];
  const float* Wp   = (const float*)d_in[3];
  const float* bp   = (const float*)d_in[4];
  const float* tt   = (const float*)d_in[5];
  const float* W1   = (const float*)d_in[6];
  const float* b1   = (const float*)d_in[7];
  const float* W2   = (const float*)d_in[8];
  const float* b2   = (const float*)d_in[9];
  const float* Wdec = (const float*)d_in[10];
  const float* bdec = (const float*)d_in[11];
  float* out = (float*)d_out;

  dim3 gridT((GG + 63) / 64, NN / 64, 1);   // 313 x 32
  transpose_convert_kernel<<<gridT, 256, 0, stream>>>(x);
  wconvert_kernel<<<(PP * 16384) / 256, 256, 0, stream>>>(Wp);

  dim3 gridA(NN / TN, NOCT, 1);             // 16 x 25
  proj_mfma_kernel<<<gridA, 256, 0, stream>>>(tidx, pidx, bp, tt);

  combine_rec_kernel<<<NN, 256, 0, stream>>>(W1, b1, W2, b2, Wdec, bdec, out);
}